// Round 14
// baseline (959.798 us; speedup 1.0000x reference)
//
#include <hip/hip_runtime.h>
#include <hip/hip_bf16.h>

using bf16x8 = __attribute__((ext_vector_type(8))) short;
using f32x4  = __attribute__((ext_vector_type(4))) float;
using f32x16 = __attribute__((ext_vector_type(16))) float;
using u32x4  = __attribute__((ext_vector_type(4))) unsigned;

constexpr int N_ = 512;

__device__ __forceinline__ unsigned pkbf(float lo, float hi) {
    unsigned a = (unsigned short)__builtin_bit_cast(short, __float2bfloat16(lo));
    unsigned b = (unsigned short)__builtin_bit_cast(short, __float2bfloat16(hi));
    return a | (b << 16);
}
__device__ __forceinline__ float bfhi2f(unsigned u) { return __builtin_bit_cast(float, u & 0xFFFF0000u); }
__device__ __forceinline__ float bflo2f(unsigned u) { return __builtin_bit_cast(float, u << 16); }
__device__ __forceinline__ void gl2lds16(const float* g, float* l) {
    __builtin_amdgcn_global_load_lds(
        (const __attribute__((address_space(1))) void*)g,
        (__attribute__((address_space(3))) void*)l, 16, 0, 0);
}

// Pre-pass: tensor[b,k,m,0..2] f32 -> ws[(b*512+k)*32+m] = {pk(x,y), pk(z,0)}
__global__ __launch_bounds__(256)
void pack_tensor(const float* __restrict__ tensor, unsigned* __restrict__ tw) {
    const int i = blockIdx.x * 256 + threadIdx.x;   // 65536 entries
    const float x = tensor[3 * i + 0];
    const float y = tensor[3 * i + 1];
    const float z = tensor[3 * i + 2];
    reinterpret_cast<uint2*>(tw)[i] = make_uint2(pkbf(x, y), pkbf(z, 0.f));
}

// ---------------- PRODUCTION kernel (R13, 28.7 us, proven) ----------------
__global__ __launch_bounds__(256, 4)
void filter_S(const unsigned* __restrict__ tw, const float* __restrict__ rbf,
              const float* __restrict__ rij, const float* __restrict__ W1,
              const float* __restrict__ b1, const float* __restrict__ W2,
              const float* __restrict__ b2, float* __restrict__ out)
{
    const int bn = blockIdx.x, b = bn >> 9, tid = threadIdx.x;
    const int lane = tid & 63, w = tid >> 6, lam = lane & 31, l5 = lane >> 5;

    __shared__ float    rbf_s[4][2][1024];
    __shared__ unsigned upk[N_][2];
    __shared__ float    red[4][32];

    const float* rij_bn = rij + (size_t)bn * (N_ * 3);
    const char*  rbf_bc = (const char*)(rbf + (size_t)bn * (N_ * 32));
    const uint2* twb    = (const uint2*)tw + (size_t)b * (N_ * 32);

    #pragma unroll
    for (int t = 0; t < 2; ++t) {
        const int k = tid + t * 256;
        const float rx = rij_bn[3 * k + 0];
        const float ry = rij_bn[3 * k + 1];
        const float rz = rij_bn[3 * k + 2];
        const float r2 = rx * rx + ry * ry + rz * rz;
        const float inv = rsqrtf(fmaxf(r2, 1e-8f));
        const float sc = (r2 >= 1e-16f) ? inv : 0.f;
        upk[k][0] = pkbf(rx * sc, ry * sc);
        upk[k][1] = pkbf(rz * sc, 0.f);
    }
    bf16x8 W1b[2];
    {
        const float* p1 = W1 + lam * 32 + 8 * l5;
        const f32x4 a0 = ((const f32x4*)p1)[0], a1 = ((const f32x4*)p1)[1];
        const f32x4 a2 = ((const f32x4*)(p1 + 16))[0], a3 = ((const f32x4*)(p1 + 16))[1];
        #pragma unroll
        for (int e = 0; e < 4; ++e) {
            W1b[0][e]     = __builtin_bit_cast(short, __float2bfloat16(a0[e]));
            W1b[0][4 + e] = __builtin_bit_cast(short, __float2bfloat16(a1[e]));
            W1b[1][e]     = __builtin_bit_cast(short, __float2bfloat16(a2[e]));
            W1b[1][4 + e] = __builtin_bit_cast(short, __float2bfloat16(a3[e]));
        }
    }
    const float b1s = b1[lam];
    __syncthreads();

    const int soff = (lane * 16) ^ (((lane >> 3) & 7) << 4);
    auto stage = [&](int t, int bufi) {
        const char* tb = rbf_bc + (size_t)(w * 4 + t) * 4096;
        float* dst = &rbf_s[w][bufi][0];
        #pragma unroll
        for (int it = 0; it < 4; ++it)
            gl2lds16((const float*)(tb + it * 1024 + soff), dst + it * 256);
    };
    stage(0, 0);

    f32x16 G;
    #pragma unroll
    for (int i = 0; i < 16; ++i) G[i] = 0.f;
    float ssum = 0.f;

    #pragma unroll
    for (int j = 0; j < 4; ++j) {
        const int e0 = (w * 4 + j) * 32;
        uint2 tv1[8], tv2[8];
        #pragma unroll
        for (int e = 0; e < 8; ++e) {
            const int k1 = e0 + 8 * l5 + e;
            tv1[e] = twb[k1 * 32 + lam];
            tv2[e] = twb[(k1 + 16) * 32 + lam];
        }
        __builtin_amdgcn_sched_barrier(0);
        if (j < 3) stage(j + 1, (j + 1) & 1);
        __builtin_amdgcn_sched_barrier(0);
        if (j < 3) asm volatile("s_waitcnt vmcnt(20)" ::: "memory");
        else       asm volatile("s_waitcnt vmcnt(16)" ::: "memory");
        __builtin_amdgcn_sched_barrier(0);

        const char* bufc = (const char*)&rbf_s[w][j & 1][0];
        const int   lin  = lam * 128 + l5 * 32;
        const int   sw   = (lam & 7) << 4;
        const f32x4 xa = *(const f32x4*)(bufc + ((lin +  0) ^ sw));
        const f32x4 xb = *(const f32x4*)(bufc + ((lin + 16) ^ sw));
        const f32x4 xc = *(const f32x4*)(bufc + ((lin + 64) ^ sw));
        const f32x4 xd = *(const f32x4*)(bufc + ((lin + 80) ^ sw));
        bf16x8 X0, X1;
        #pragma unroll
        for (int e = 0; e < 4; ++e) {
            X0[e]     = __builtin_bit_cast(short, __float2bfloat16(xa[e]));
            X0[4 + e] = __builtin_bit_cast(short, __float2bfloat16(xb[e]));
            X1[e]     = __builtin_bit_cast(short, __float2bfloat16(xc[e]));
            X1[4 + e] = __builtin_bit_cast(short, __float2bfloat16(xd[e]));
        }
        f32x16 h;
        #pragma unroll
        for (int i = 0; i < 16; ++i) h[i] = 0.f;
        h = __builtin_amdgcn_mfma_f32_32x32x16_bf16(X0, W1b[0], h, 0, 0, 0);
        h = __builtin_amdgcn_mfma_f32_32x32x16_bf16(X1, W1b[1], h, 0, 0, 0);
        unsigned P0, P1, P2, P3, P4, P5, P6, P7;
        {
            const float t0 = fmaxf(h[0] + b1s, 0.f),  t1v = fmaxf(h[1] + b1s, 0.f);
            const float t2v = fmaxf(h[2] + b1s, 0.f), t3 = fmaxf(h[3] + b1s, 0.f);
            const float t4 = fmaxf(h[4] + b1s, 0.f),  t5 = fmaxf(h[5] + b1s, 0.f);
            const float t6 = fmaxf(h[6] + b1s, 0.f),  t7 = fmaxf(h[7] + b1s, 0.f);
            const float t8 = fmaxf(h[8] + b1s, 0.f),  t9 = fmaxf(h[9] + b1s, 0.f);
            const float tA = fmaxf(h[10] + b1s, 0.f), tB = fmaxf(h[11] + b1s, 0.f);
            const float tC = fmaxf(h[12] + b1s, 0.f), tD = fmaxf(h[13] + b1s, 0.f);
            const float tE = fmaxf(h[14] + b1s, 0.f), tF = fmaxf(h[15] + b1s, 0.f);
            P0 = pkbf(t0, t1v); P1 = pkbf(t2v, t3);
            P2 = pkbf(t4, t5);  P3 = pkbf(t6, t7);
            P4 = pkbf(t8, t9);  P5 = pkbf(tA, tB);
            P6 = pkbf(tC, tD);  P7 = pkbf(tE, tF);
        }
        const unsigned Q0 = __shfl_xor(P0, 32, 64);
        const unsigned Q1 = __shfl_xor(P1, 32, 64);
        const unsigned Q2 = __shfl_xor(P2, 32, 64);
        const unsigned Q3 = __shfl_xor(P3, 32, 64);
        const unsigned Q4 = __shfl_xor(P4, 32, 64);
        const unsigned Q5 = __shfl_xor(P5, 32, 64);
        const unsigned Q6 = __shfl_xor(P6, 32, 64);
        const unsigned Q7 = __shfl_xor(P7, 32, 64);
        const bool lo = (l5 == 0);
        const u32x4 A1 = { lo ? P0 : Q2, lo ? P1 : Q3, lo ? Q0 : P2, lo ? Q1 : P3 };
        const u32x4 A2 = { lo ? P4 : Q6, lo ? P5 : Q7, lo ? Q4 : P6, lo ? Q5 : P7 };

        u32x4 B1d, B2d;
        float sp;
        #pragma unroll
        for (int e = 0; e < 8; ++e) {
            const int kl = 8 * l5 + e;
            const unsigned u0 = upk[e0 + kl][0], u1 = upk[e0 + kl][1];
            const float s = bflo2f(u0) * bflo2f(tv1[e].x) + bfhi2f(u0) * bfhi2f(tv1[e].x)
                          + bflo2f(u1) * bflo2f(tv1[e].y);
            ssum += s;
            if (e & 1) B1d[e >> 1] = pkbf(sp, s); else sp = s;
        }
        #pragma unroll
        for (int e = 0; e < 8; ++e) {
            const int kl = 16 + 8 * l5 + e;
            const unsigned u0 = upk[e0 + kl][0], u1 = upk[e0 + kl][1];
            const float s = bflo2f(u0) * bflo2f(tv2[e].x) + bfhi2f(u0) * bfhi2f(tv2[e].x)
                          + bflo2f(u1) * bflo2f(tv2[e].y);
            ssum += s;
            if (e & 1) B2d[e >> 1] = pkbf(sp, s); else sp = s;
        }

        G = __builtin_amdgcn_mfma_f32_32x32x16_bf16(
                __builtin_bit_cast(bf16x8, A1), __builtin_bit_cast(bf16x8, B1d), G, 0, 0, 0);
        G = __builtin_amdgcn_mfma_f32_32x32x16_bf16(
                __builtin_bit_cast(bf16x8, A2), __builtin_bit_cast(bf16x8, B2d), G, 0, 0, 0);
    }

    float p = 0.f;
    #pragma unroll
    for (int q = 0; q < 4; ++q) {
        const f32x4 wv = *(const f32x4*)(W2 + lam * 32 + 8 * q + 4 * l5);
        p += wv[0] * G[4 * q + 0] + wv[1] * G[4 * q + 1]
           + wv[2] * G[4 * q + 2] + wv[3] * G[4 * q + 3];
    }
    p    += __shfl_xor(p, 32, 64);
    ssum += __shfl_xor(ssum, 32, 64);
    const float o = p + b2[lam] * ssum;
    if (l5 == 0) red[w][lam] = o;
    __syncthreads();
    if (tid < 32)
        out[bn * 32 + tid] = red[0][tid] + red[1][tid] + red[2][tid] + red[3][tid];
}

// ---------------- ABLATION kernels (diagnostic, write to ws) ----------------
// Based on the simple R12 direct-load structure (30.6 us, same plateau).
// V0=full  V1=no S-path (tensor loads+dots stubbed)  V2=no H-path (rbf+MFMA1+
// pack+shfl stubbed)  V3=loads only (no MFMA/pack).  REP iterations with a
// laundered rep index so loads can't be CSE'd across reps (rule #17).
template <int V, int REP>
__global__ __launch_bounds__(256, 4)
void filter_abl(const unsigned* __restrict__ tw, const float* __restrict__ rbf,
                const float* __restrict__ rij, const float* __restrict__ W1,
                const float* __restrict__ b1, float* __restrict__ wsout)
{
    const int bn = blockIdx.x, b = bn >> 9, tid = threadIdx.x;
    const int lane = tid & 63, w = tid >> 6, lam = lane & 31, l5 = lane >> 5;

    __shared__ unsigned upk[N_][2];

    const float* rij_bn = rij + (size_t)bn * (N_ * 3);
    const float* rbf_bn = rbf + (size_t)bn * (N_ * 32);
    const uint2* twb    = (const uint2*)tw + (size_t)b * (N_ * 32);

    #pragma unroll
    for (int t = 0; t < 2; ++t) {
        const int k = tid + t * 256;
        const float rx = rij_bn[3 * k + 0];
        const float ry = rij_bn[3 * k + 1];
        const float rz = rij_bn[3 * k + 2];
        const float r2 = rx * rx + ry * ry + rz * rz;
        const float inv = rsqrtf(fmaxf(r2, 1e-8f));
        const float sc = (r2 >= 1e-16f) ? inv : 0.f;
        upk[k][0] = pkbf(rx * sc, ry * sc);
        upk[k][1] = pkbf(rz * sc, 0.f);
    }
    bf16x8 W1b[2];
    {
        const float* p1 = W1 + lam * 32 + 8 * l5;
        const f32x4 a0 = ((const f32x4*)p1)[0], a1 = ((const f32x4*)p1)[1];
        const f32x4 a2 = ((const f32x4*)(p1 + 16))[0], a3 = ((const f32x4*)(p1 + 16))[1];
        #pragma unroll
        for (int e = 0; e < 4; ++e) {
            W1b[0][e]     = __builtin_bit_cast(short, __float2bfloat16(a0[e]));
            W1b[0][4 + e] = __builtin_bit_cast(short, __float2bfloat16(a1[e]));
            W1b[1][e]     = __builtin_bit_cast(short, __float2bfloat16(a2[e]));
            W1b[1][4 + e] = __builtin_bit_cast(short, __float2bfloat16(a3[e]));
        }
    }
    const float b1s = b1[lam];
    __syncthreads();

    f32x16 G;
    #pragma unroll
    for (int i = 0; i < 16; ++i) G[i] = 0.f;
    float ssum = 0.f;

    for (int r = 0; r < REP; ++r) {
        int rl;
        asm volatile("v_mov_b32 %0, %1" : "=v"(rl) : "v"(r));   // launder rep
        #pragma unroll
        for (int j = 0; j < 4; ++j) {
            const int jj = (j + rl) & 3;
            const int e0 = (w * 4 + jj) * 32;

            uint2 tv1[8], tv2[8];
            if constexpr (V != 1) {   // S-path loads
                #pragma unroll
                for (int e = 0; e < 8; ++e) {
                    const int k1 = e0 + 8 * l5 + e;
                    tv1[e] = twb[k1 * 32 + lam];
                    tv2[e] = twb[(k1 + 16) * 32 + lam];
                }
            }

            f32x4 xa, xb, xc, xd;
            bf16x8 X0, X1;
            if constexpr (V != 2) {   // H-path loads + cvt
                const float* ap = rbf_bn + (size_t)(e0 + lam) * 32 + 8 * l5;
                xa = ((const f32x4*)ap)[0];
                xb = ((const f32x4*)ap)[1];
                xc = ((const f32x4*)(ap + 16))[0];
                xd = ((const f32x4*)(ap + 16))[1];
                #pragma unroll
                for (int e = 0; e < 4; ++e) {
                    X0[e]     = __builtin_bit_cast(short, __float2bfloat16(xa[e]));
                    X0[4 + e] = __builtin_bit_cast(short, __float2bfloat16(xb[e]));
                    X1[e]     = __builtin_bit_cast(short, __float2bfloat16(xc[e]));
                    X1[4 + e] = __builtin_bit_cast(short, __float2bfloat16(xd[e]));
                }
            }

            if constexpr (V == 3) {   // loads only; keep live, no compute
                ssum += xa[0] + xb[1] + xc[2] + xd[3];
                #pragma unroll
                for (int e = 0; e < 8; ++e)
                    ssum += bflo2f(tv1[e].x) + bfhi2f(tv2[e].y);
            } else {
                u32x4 A1, A2;
                if constexpr (V != 2) {
                    f32x16 h;
                    #pragma unroll
                    for (int i = 0; i < 16; ++i) h[i] = 0.f;
                    h = __builtin_amdgcn_mfma_f32_32x32x16_bf16(X0, W1b[0], h, 0, 0, 0);
                    h = __builtin_amdgcn_mfma_f32_32x32x16_bf16(X1, W1b[1], h, 0, 0, 0);
                    unsigned P0, P1, P2, P3, P4, P5, P6, P7;
                    {
                        const float t0 = fmaxf(h[0] + b1s, 0.f),  t1v = fmaxf(h[1] + b1s, 0.f);
                        const float t2v = fmaxf(h[2] + b1s, 0.f), t3 = fmaxf(h[3] + b1s, 0.f);
                        const float t4 = fmaxf(h[4] + b1s, 0.f),  t5 = fmaxf(h[5] + b1s, 0.f);
                        const float t6 = fmaxf(h[6] + b1s, 0.f),  t7 = fmaxf(h[7] + b1s, 0.f);
                        const float t8 = fmaxf(h[8] + b1s, 0.f),  t9 = fmaxf(h[9] + b1s, 0.f);
                        const float tA = fmaxf(h[10] + b1s, 0.f), tB = fmaxf(h[11] + b1s, 0.f);
                        const float tC = fmaxf(h[12] + b1s, 0.f), tD = fmaxf(h[13] + b1s, 0.f);
                        const float tE = fmaxf(h[14] + b1s, 0.f), tF = fmaxf(h[15] + b1s, 0.f);
                        P0 = pkbf(t0, t1v); P1 = pkbf(t2v, t3);
                        P2 = pkbf(t4, t5);  P3 = pkbf(t6, t7);
                        P4 = pkbf(t8, t9);  P5 = pkbf(tA, tB);
                        P6 = pkbf(tC, tD);  P7 = pkbf(tE, tF);
                    }
                    const unsigned Q0 = __shfl_xor(P0, 32, 64);
                    const unsigned Q1 = __shfl_xor(P1, 32, 64);
                    const unsigned Q2 = __shfl_xor(P2, 32, 64);
                    const unsigned Q3 = __shfl_xor(P3, 32, 64);
                    const unsigned Q4 = __shfl_xor(P4, 32, 64);
                    const unsigned Q5 = __shfl_xor(P5, 32, 64);
                    const unsigned Q6 = __shfl_xor(P6, 32, 64);
                    const unsigned Q7 = __shfl_xor(P7, 32, 64);
                    const bool lo = (l5 == 0);
                    A1 = u32x4{ lo ? P0 : Q2, lo ? P1 : Q3, lo ? Q0 : P2, lo ? Q1 : P3 };
                    A2 = u32x4{ lo ? P4 : Q6, lo ? P5 : Q7, lo ? Q4 : P6, lo ? Q5 : P7 };
                } else {
                    A1 = __builtin_bit_cast(u32x4, W1b[0]);
                    A2 = __builtin_bit_cast(u32x4, W1b[1]);
                }
                u32x4 B1d, B2d;
                if constexpr (V != 1) {
                    float sp;
                    #pragma unroll
                    for (int e = 0; e < 8; ++e) {
                        const int kl = 8 * l5 + e;
                        const unsigned u0 = upk[e0 + kl][0], u1 = upk[e0 + kl][1];
                        const float s = bflo2f(u0) * bflo2f(tv1[e].x)
                                      + bfhi2f(u0) * bfhi2f(tv1[e].x)
                                      + bflo2f(u1) * bflo2f(tv1[e].y);
                        ssum += s;
                        if (e & 1) B1d[e >> 1] = pkbf(sp, s); else sp = s;
                    }
                    #pragma unroll
                    for (int e = 0; e < 8; ++e) {
                        const int kl = 16 + 8 * l5 + e;
                        const unsigned u0 = upk[e0 + kl][0], u1 = upk[e0 + kl][1];
                        const float s = bflo2f(u0) * bflo2f(tv2[e].x)
                                      + bfhi2f(u0) * bfhi2f(tv2[e].x)
                                      + bflo2f(u1) * bflo2f(tv2[e].y);
                        ssum += s;
                        if (e & 1) B2d[e >> 1] = pkbf(sp, s); else sp = s;
                    }
                } else {
                    B1d = __builtin_bit_cast(u32x4, W1b[0]);
                    B2d = __builtin_bit_cast(u32x4, W1b[1]);
                }
                G = __builtin_amdgcn_mfma_f32_32x32x16_bf16(
                        __builtin_bit_cast(bf16x8, A1), __builtin_bit_cast(bf16x8, B1d), G, 0, 0, 0);
                G = __builtin_amdgcn_mfma_f32_32x32x16_bf16(
                        __builtin_bit_cast(bf16x8, A2), __builtin_bit_cast(bf16x8, B2d), G, 0, 0, 0);
            }
        }
    }

    float acc = ssum;
    #pragma unroll
    for (int i = 0; i < 16; ++i) acc += G[i];
    wsout[(size_t)bn * 256 + tid] = acc;
}

// ---------- fallback (R10 kernel, f32 LDS staging, no ws needed) ----------
__global__ __launch_bounds__(256, 4)
void filter_L(const float* __restrict__ tensor, const float* __restrict__ rbf,
              const float* __restrict__ rij, const float* __restrict__ W1,
              const float* __restrict__ b1, const float* __restrict__ W2,
              const float* __restrict__ b2, float* __restrict__ out)
{
    const int bn = blockIdx.x, b = bn >> 9, tid = threadIdx.x;
    const int lane = tid & 63, w = tid >> 6, lam = lane & 31, l5 = lane >> 5;
    __shared__ float Ts[4][3072];
    __shared__ unsigned upk[N_][2];
    __shared__ float red[4][32];
    const float* rij_bn = rij + (size_t)bn * (N_ * 3);
    const float* rbf_bn = rbf + (size_t)bn * (N_ * 32);
    const float* ten_b  = tensor + (size_t)b * (N_ * 32 * 3);
    #pragma unroll
    for (int t = 0; t < 2; ++t) {
        const int k = tid + t * 256;
        const float rx = rij_bn[3 * k], ry = rij_bn[3 * k + 1], rz = rij_bn[3 * k + 2];
        const float r2 = rx * rx + ry * ry + rz * rz;
        const float inv = rsqrtf(fmaxf(r2, 1e-8f));
        const float sc = (r2 >= 1e-16f) ? inv : 0.f;
        upk[k][0] = pkbf(rx * sc, ry * sc);
        upk[k][1] = pkbf(rz * sc, 0.f);
    }
    bf16x8 W1b[2];
    {
        const float* p1 = W1 + lam * 32 + 8 * l5;
        const f32x4 a0 = ((const f32x4*)p1)[0], a1 = ((const f32x4*)p1)[1];
        const f32x4 a2 = ((const f32x4*)(p1 + 16))[0], a3 = ((const f32x4*)(p1 + 16))[1];
        #pragma unroll
        for (int e = 0; e < 4; ++e) {
            W1b[0][e] = __builtin_bit_cast(short, __float2bfloat16(a0[e]));
            W1b[0][4 + e] = __builtin_bit_cast(short, __float2bfloat16(a1[e]));
            W1b[1][e] = __builtin_bit_cast(short, __float2bfloat16(a2[e]));
            W1b[1][4 + e] = __builtin_bit_cast(short, __float2bfloat16(a3[e]));
        }
    }
    const float b1s = b1[lam];
    __syncthreads();
    float* tsw = &Ts[w][0];
    f32x4 xa[2], xb[2], xc[2], xd[2];
    {
        const float* ap = rbf_bn + (size_t)(w * 128 + lam) * 32 + 8 * l5;
        xa[0] = ((const f32x4*)ap)[0]; xb[0] = ((const f32x4*)ap)[1];
        xc[0] = ((const f32x4*)(ap + 16))[0]; xd[0] = ((const f32x4*)(ap + 16))[1];
    }
    {
        const float* gsrc = ten_b + (size_t)(w * 128) * 96;
        #pragma unroll
        for (int it = 0; it < 12; ++it) gl2lds16(gsrc + it * 256 + lane * 4, tsw + it * 256);
    }
    f32x16 G;
    #pragma unroll
    for (int i = 0; i < 16; ++i) G[i] = 0.f;
    float ssum = 0.f;
    #pragma unroll
    for (int j = 0; j < 4; ++j) {
        const int e0 = (w * 4 + j) * 32, cur = j & 1, nx = cur ^ 1;
        bf16x8 X0, X1;
        #pragma unroll
        for (int e = 0; e < 4; ++e) {
            X0[e] = __builtin_bit_cast(short, __float2bfloat16(xa[cur][e]));
            X0[4 + e] = __builtin_bit_cast(short, __float2bfloat16(xb[cur][e]));
            X1[e] = __builtin_bit_cast(short, __float2bfloat16(xc[cur][e]));
            X1[4 + e] = __builtin_bit_cast(short, __float2bfloat16(xd[cur][e]));
        }
        if (j < 3) {
            const float* ap = rbf_bn + (size_t)(e0 + 32 + lam) * 32 + 8 * l5;
            xa[nx] = ((const f32x4*)ap)[0]; xb[nx] = ((const f32x4*)ap)[1];
            xc[nx] = ((const f32x4*)(ap + 16))[0]; xd[nx] = ((const f32x4*)(ap + 16))[1];
        }
        f32x16 h;
        #pragma unroll
        for (int i = 0; i < 16; ++i) h[i] = 0.f;
        h = __builtin_amdgcn_mfma_f32_32x32x16_bf16(X0, W1b[0], h, 0, 0, 0);
        h = __builtin_amdgcn_mfma_f32_32x32x16_bf16(X1, W1b[1], h, 0, 0, 0);
        unsigned P0, P1, P2, P3, P4, P5, P6, P7;
        {
            const float t0 = fmaxf(h[0] + b1s, 0.f), t1v = fmaxf(h[1] + b1s, 0.f);
            const float t2v = fmaxf(h[2] + b1s, 0.f), t3 = fmaxf(h[3] + b1s, 0.f);
            const float t4 = fmaxf(h[4] + b1s, 0.f), t5 = fmaxf(h[5] + b1s, 0.f);
            const float t6 = fmaxf(h[6] + b1s, 0.f), t7 = fmaxf(h[7] + b1s, 0.f);
            const float t8 = fmaxf(h[8] + b1s, 0.f), t9 = fmaxf(h[9] + b1s, 0.f);
            const float tA = fmaxf(h[10] + b1s, 0.f), tB = fmaxf(h[11] + b1s, 0.f);
            const float tC = fmaxf(h[12] + b1s, 0.f), tD = fmaxf(h[13] + b1s, 0.f);
            const float tE = fmaxf(h[14] + b1s, 0.f), tF = fmaxf(h[15] + b1s, 0.f);
            P0 = pkbf(t0, t1v); P1 = pkbf(t2v, t3); P2 = pkbf(t4, t5); P3 = pkbf(t6, t7);
            P4 = pkbf(t8, t9); P5 = pkbf(tA, tB); P6 = pkbf(tC, tD); P7 = pkbf(tE, tF);
        }
        const unsigned Q0 = __shfl_xor(P0, 32, 64), Q1 = __shfl_xor(P1, 32, 64);
        const unsigned Q2 = __shfl_xor(P2, 32, 64), Q3 = __shfl_xor(P3, 32, 64);
        const unsigned Q4 = __shfl_xor(P4, 32, 64), Q5 = __shfl_xor(P5, 32, 64);
        const unsigned Q6 = __shfl_xor(P6, 32, 64), Q7 = __shfl_xor(P7, 32, 64);
        const bool lo = (l5 == 0);
        const u32x4 A1 = { lo ? P0 : Q2, lo ? P1 : Q3, lo ? Q0 : P2, lo ? Q1 : P3 };
        const u32x4 A2 = { lo ? P4 : Q6, lo ? P5 : Q7, lo ? Q4 : P6, lo ? Q5 : P7 };
        if (j < 3) asm volatile("s_waitcnt vmcnt(4)" ::: "memory");
        else       asm volatile("s_waitcnt vmcnt(0)" ::: "memory");
        u32x4 B1d, B2d;
        float sp;
        #pragma unroll
        for (int e = 0; e < 8; ++e) {
            const int kl = 8 * l5 + e;
            const unsigned u0 = upk[e0 + kl][0], u1 = upk[e0 + kl][1];
            const float* tq = tsw + kl * 96 + 3 * lam;
            const float s = bflo2f(u0) * tq[0] + bfhi2f(u0) * tq[1] + bflo2f(u1) * tq[2];
            ssum += s;
            if (e & 1) B1d[e >> 1] = pkbf(sp, s); else sp = s;
        }
        #pragma unroll
        for (int e = 0; e < 8; ++e) {
            const int kl = 16 + 8 * l5 + e;
            const unsigned u0 = upk[e0 + kl][0], u1 = upk[e0 + kl][1];
            const float* tq = tsw + kl * 96 + 3 * lam;
            const float s = bflo2f(u0) * tq[0] + bfhi2f(u0) * tq[1] + bflo2f(u1) * tq[2];
            ssum += s;
            if (e & 1) B2d[e >> 1] = pkbf(sp, s); else sp = s;
        }
        asm volatile("s_waitcnt lgkmcnt(0)" ::: "memory");
        if (j < 3) {
            const float* gsrc = ten_b + (size_t)(e0 + 32) * 96;
            #pragma unroll
            for (int it = 0; it < 12; ++it) gl2lds16(gsrc + it * 256 + lane * 4, tsw + it * 256);
        }
        G = __builtin_amdgcn_mfma_f32_32x32x16_bf16(
                __builtin_bit_cast(bf16x8, A1), __builtin_bit_cast(bf16x8, B1d), G, 0, 0, 0);
        G = __builtin_amdgcn_mfma_f32_32x32x16_bf16(
                __builtin_bit_cast(bf16x8, A2), __builtin_bit_cast(bf16x8, B2d), G, 0, 0, 0);
    }
    float p = 0.f;
    #pragma unroll
    for (int q = 0; q < 4; ++q) {
        const f32x4 wv = *(const f32x4*)(W2 + lam * 32 + 8 * q + 4 * l5);
        p += wv[0] * G[4 * q + 0] + wv[1] * G[4 * q + 1]
           + wv[2] * G[4 * q + 2] + wv[3] * G[4 * q + 3];
    }
    p    += __shfl_xor(p, 32, 64);
    ssum += __shfl_xor(ssum, 32, 64);
    const float o = p + b2[lam] * ssum;
    if (l5 == 0) red[w][lam] = o;
    __syncthreads();
    if (tid < 32)
        out[bn * 32 + tid] = red[0][tid] + red[1][tid] + red[2][tid] + red[3][tid];
}

extern "C" void kernel_launch(void* const* d_in, const int* in_sizes, int n_in,
                              void* d_out, int out_size, void* d_ws, size_t ws_size,
                              hipStream_t stream) {
    const float* tensor = (const float*)d_in[0];
    const float* rbf    = (const float*)d_in[1];
    const float* rij    = (const float*)d_in[2];
    const float* W1     = (const float*)d_in[3];
    const float* b1     = (const float*)d_in[4];
    const float* W2     = (const float*)d_in[5];
    const float* b2     = (const float*)d_in[6];
    float* out = (float*)d_out;

    const size_t ws_need = (size_t)2 * N_ * 32 * 2 * sizeof(unsigned);   // 512 KB
    dim3 block(256), grid(2 * N_);
    if (ws_size >= ws_need) {
        unsigned* tw = (unsigned*)d_ws;
        pack_tensor<<<dim3(256), block, 0, stream>>>(tensor, tw);
        filter_S<<<grid, block, 0, stream>>>(tw, rbf, rij, W1, b1, W2, b2, out);
        // Diagnostic ablations (write to ws; do not affect out).
        if (ws_size >= (8u << 20)) {
            float* abl = (float*)((char*)d_ws + (1 << 20));
            filter_abl<0, 20><<<grid, block, 0, stream>>>(tw, rbf, rij, W1, b1, abl + 0 * 262144);
            filter_abl<1, 20><<<grid, block, 0, stream>>>(tw, rbf, rij, W1, b1, abl + 1 * 262144);
            filter_abl<2, 20><<<grid, block, 0, stream>>>(tw, rbf, rij, W1, b1, abl + 2 * 262144);
            filter_abl<3, 20><<<grid, block, 0, stream>>>(tw, rbf, rij, W1, b1, abl + 3 * 262144);
        }
    } else {
        filter_L<<<grid, block, 0, stream>>>(tensor, rbf, rij, W1, b1, W2, b2, out);
    }
}

// Round 16
// 28.640 us; speedup vs baseline: 33.5121x; 33.5121x over previous
//
#include <hip/hip_runtime.h>
#include <hip/hip_bf16.h>

using bf16x8 = __attribute__((ext_vector_type(8))) short;
using f32x4  = __attribute__((ext_vector_type(4))) float;
using f32x16 = __attribute__((ext_vector_type(16))) float;
using u32x4  = __attribute__((ext_vector_type(4))) unsigned;

constexpr int N_ = 512;

__device__ __forceinline__ unsigned pkbf(float lo, float hi) {
    unsigned a = (unsigned short)__builtin_bit_cast(short, __float2bfloat16(lo));
    unsigned b = (unsigned short)__builtin_bit_cast(short, __float2bfloat16(hi));
    return a | (b << 16);
}
__device__ __forceinline__ float bfhi2f(unsigned u) { return __builtin_bit_cast(float, u & 0xFFFF0000u); }
__device__ __forceinline__ float bflo2f(unsigned u) { return __builtin_bit_cast(float, u << 16); }
__device__ __forceinline__ void gl2lds16(const float* g, float* l) {
    __builtin_amdgcn_global_load_lds(
        (const __attribute__((address_space(1))) void*)g,
        (__attribute__((address_space(3))) void*)l, 16, 0, 0);
}

// Pre-pass: tensor[b,k,m,0..2] f32 -> ws[(b*512+k)*32+m] = {pk(x,y), pk(z,0)}
__global__ __launch_bounds__(256)
void pack_tensor(const float* __restrict__ tensor, unsigned* __restrict__ tw) {
    const int i = blockIdx.x * 256 + threadIdx.x;   // 65536 entries
    const float x = tensor[3 * i + 0];
    const float y = tensor[3 * i + 1];
    const float z = tensor[3 * i + 2];
    reinterpret_cast<uint2*>(tw)[i] = make_uint2(pkbf(x, y), pkbf(z, 0.f));
}

// ---------------- PRODUCTION kernel (R13-exact, 28.7 us, proven) ----------------
// Factorized: out[m] = sum_l W2[m,l]*G[l,m] + b2[m]*sum_k S[k,m]
//   S[k,m] = u_k . T[b,k,m,:] (bf16-packed), G = sum_k H[k,l]*S[k,m] via MFMA K=512.
// rbf staged via swizzled global_load_lds (both-sides involution), double-buffered,
// counted vmcnt (20/16) -- never drains tensor loads mid-loop.
__global__ __launch_bounds__(256, 4)
void filter_S(const unsigned* __restrict__ tw, const float* __restrict__ rbf,
              const float* __restrict__ rij, const float* __restrict__ W1,
              const float* __restrict__ b1, const float* __restrict__ W2,
              const float* __restrict__ b2, float* __restrict__ out)
{
    const int bn = blockIdx.x, b = bn >> 9, tid = threadIdx.x;
    const int lane = tid & 63, w = tid >> 6, lam = lane & 31, l5 = lane >> 5;

    __shared__ float    rbf_s[4][2][1024];
    __shared__ unsigned upk[N_][2];
    __shared__ float    red[4][32];

    const float* rij_bn = rij + (size_t)bn * (N_ * 3);
    const char*  rbf_bc = (const char*)(rbf + (size_t)bn * (N_ * 32));
    const uint2* twb    = (const uint2*)tw + (size_t)b * (N_ * 32);

    #pragma unroll
    for (int t = 0; t < 2; ++t) {
        const int k = tid + t * 256;
        const float rx = rij_bn[3 * k + 0];
        const float ry = rij_bn[3 * k + 1];
        const float rz = rij_bn[3 * k + 2];
        const float r2 = rx * rx + ry * ry + rz * rz;
        const float inv = rsqrtf(fmaxf(r2, 1e-8f));
        const float sc = (r2 >= 1e-16f) ? inv : 0.f;   // |rij| >= 1e-8 mask
        upk[k][0] = pkbf(rx * sc, ry * sc);
        upk[k][1] = pkbf(rz * sc, 0.f);
    }
    bf16x8 W1b[2];
    {
        const float* p1 = W1 + lam * 32 + 8 * l5;
        const f32x4 a0 = ((const f32x4*)p1)[0], a1 = ((const f32x4*)p1)[1];
        const f32x4 a2 = ((const f32x4*)(p1 + 16))[0], a3 = ((const f32x4*)(p1 + 16))[1];
        #pragma unroll
        for (int e = 0; e < 4; ++e) {
            W1b[0][e]     = __builtin_bit_cast(short, __float2bfloat16(a0[e]));
            W1b[0][4 + e] = __builtin_bit_cast(short, __float2bfloat16(a1[e]));
            W1b[1][e]     = __builtin_bit_cast(short, __float2bfloat16(a2[e]));
            W1b[1][4 + e] = __builtin_bit_cast(short, __float2bfloat16(a3[e]));
        }
    }
    const float b1s = b1[lam];
    __syncthreads();

    // Per-lane staging source byte-offset: linear dest lane*16, pre-swizzled
    // source with the SAME involution the read side applies (rule #21).
    const int soff = (lane * 16) ^ (((lane >> 3) & 7) << 4);
    auto stage = [&](int t, int bufi) {
        const char* tb = rbf_bc + (size_t)(w * 4 + t) * 4096;
        float* dst = &rbf_s[w][bufi][0];
        #pragma unroll
        for (int it = 0; it < 4; ++it)
            gl2lds16((const float*)(tb + it * 1024 + soff), dst + it * 256);
    };
    stage(0, 0);

    f32x16 G;
    #pragma unroll
    for (int i = 0; i < 16; ++i) G[i] = 0.f;
    float ssum = 0.f;

    #pragma unroll
    for (int j = 0; j < 4; ++j) {
        const int e0 = (w * 4 + j) * 32;

        // (a) tensor loads for tile j (16 dwordx2, consumed late in S-path).
        uint2 tv1[8], tv2[8];
        #pragma unroll
        for (int e = 0; e < 8; ++e) {
            const int k1 = e0 + 8 * l5 + e;
            tv1[e] = twb[k1 * 32 + lam];
            tv2[e] = twb[(k1 + 16) * 32 + lam];
        }
        __builtin_amdgcn_sched_barrier(0);

        // (b) stage next tile into the other buffer.
        if (j < 3) stage(j + 1, (j + 1) & 1);
        __builtin_amdgcn_sched_barrier(0);

        // (c) drain ONLY tile j's staging (4 oldest). Outstanding at wait:
        //     stage_j(4) + tensor_j(16) [+ stage_{j+1}(4) if j<3].
        if (j < 3) asm volatile("s_waitcnt vmcnt(20)" ::: "memory");
        else       asm volatile("s_waitcnt vmcnt(16)" ::: "memory");
        __builtin_amdgcn_sched_barrier(0);

        // H-path: swizzled ds_read_b128.
        const char* bufc = (const char*)&rbf_s[w][j & 1][0];
        const int   lin  = lam * 128 + l5 * 32;
        const int   sw   = (lam & 7) << 4;
        const f32x4 xa = *(const f32x4*)(bufc + ((lin +  0) ^ sw));
        const f32x4 xb = *(const f32x4*)(bufc + ((lin + 16) ^ sw));
        const f32x4 xc = *(const f32x4*)(bufc + ((lin + 64) ^ sw));
        const f32x4 xd = *(const f32x4*)(bufc + ((lin + 80) ^ sw));
        bf16x8 X0, X1;
        #pragma unroll
        for (int e = 0; e < 4; ++e) {
            X0[e]     = __builtin_bit_cast(short, __float2bfloat16(xa[e]));
            X0[4 + e] = __builtin_bit_cast(short, __float2bfloat16(xb[e]));
            X1[e]     = __builtin_bit_cast(short, __float2bfloat16(xc[e]));
            X1[4 + e] = __builtin_bit_cast(short, __float2bfloat16(xd[e]));
        }

        // Layer 1: H[edge][ch]
        f32x16 h;
        #pragma unroll
        for (int i = 0; i < 16; ++i) h[i] = 0.f;
        h = __builtin_amdgcn_mfma_f32_32x32x16_bf16(X0, W1b[0], h, 0, 0, 0);
        h = __builtin_amdgcn_mfma_f32_32x32x16_bf16(X1, W1b[1], h, 0, 0, 0);

        // bias + relu + pack pairs (reg r -> edge (r&3)+8*(r>>2)+4*l5, ch lam)
        unsigned P0, P1, P2, P3, P4, P5, P6, P7;
        {
            const float t0 = fmaxf(h[0] + b1s, 0.f),  t1v = fmaxf(h[1] + b1s, 0.f);
            const float t2v = fmaxf(h[2] + b1s, 0.f), t3 = fmaxf(h[3] + b1s, 0.f);
            const float t4 = fmaxf(h[4] + b1s, 0.f),  t5 = fmaxf(h[5] + b1s, 0.f);
            const float t6 = fmaxf(h[6] + b1s, 0.f),  t7 = fmaxf(h[7] + b1s, 0.f);
            const float t8 = fmaxf(h[8] + b1s, 0.f),  t9 = fmaxf(h[9] + b1s, 0.f);
            const float tA = fmaxf(h[10] + b1s, 0.f), tB = fmaxf(h[11] + b1s, 0.f);
            const float tC = fmaxf(h[12] + b1s, 0.f), tD = fmaxf(h[13] + b1s, 0.f);
            const float tE = fmaxf(h[14] + b1s, 0.f), tF = fmaxf(h[15] + b1s, 0.f);
            P0 = pkbf(t0, t1v); P1 = pkbf(t2v, t3);
            P2 = pkbf(t4, t5);  P3 = pkbf(t6, t7);
            P4 = pkbf(t8, t9);  P5 = pkbf(tA, tB);
            P6 = pkbf(tC, tD);  P7 = pkbf(tE, tF);
        }
        // proven half-swap -> A-frags (k-dim = edge)
        const unsigned Q0 = __shfl_xor(P0, 32, 64);
        const unsigned Q1 = __shfl_xor(P1, 32, 64);
        const unsigned Q2 = __shfl_xor(P2, 32, 64);
        const unsigned Q3 = __shfl_xor(P3, 32, 64);
        const unsigned Q4 = __shfl_xor(P4, 32, 64);
        const unsigned Q5 = __shfl_xor(P5, 32, 64);
        const unsigned Q6 = __shfl_xor(P6, 32, 64);
        const unsigned Q7 = __shfl_xor(P7, 32, 64);
        const bool lo = (l5 == 0);
        const u32x4 A1 = { lo ? P0 : Q2, lo ? P1 : Q3, lo ? Q0 : P2, lo ? Q1 : P3 };
        const u32x4 A2 = { lo ? P4 : Q6, lo ? P5 : Q7, lo ? Q4 : P6, lo ? Q5 : P7 };

        // S-path from registers (tensor loads landed under the H-path).
        u32x4 B1d, B2d;
        float sp;
        #pragma unroll
        for (int e = 0; e < 8; ++e) {
            const int kl = 8 * l5 + e;
            const unsigned u0 = upk[e0 + kl][0], u1 = upk[e0 + kl][1];
            const float s = bflo2f(u0) * bflo2f(tv1[e].x) + bfhi2f(u0) * bfhi2f(tv1[e].x)
                          + bflo2f(u1) * bflo2f(tv1[e].y);
            ssum += s;
            if (e & 1) B1d[e >> 1] = pkbf(sp, s); else sp = s;
        }
        #pragma unroll
        for (int e = 0; e < 8; ++e) {
            const int kl = 16 + 8 * l5 + e;
            const unsigned u0 = upk[e0 + kl][0], u1 = upk[e0 + kl][1];
            const float s = bflo2f(u0) * bflo2f(tv2[e].x) + bfhi2f(u0) * bfhi2f(tv2[e].x)
                          + bflo2f(u1) * bflo2f(tv2[e].y);
            ssum += s;
            if (e & 1) B2d[e >> 1] = pkbf(sp, s); else sp = s;
        }

        G = __builtin_amdgcn_mfma_f32_32x32x16_bf16(
                __builtin_bit_cast(bf16x8, A1), __builtin_bit_cast(bf16x8, B1d), G, 0, 0, 0);
        G = __builtin_amdgcn_mfma_f32_32x32x16_bf16(
                __builtin_bit_cast(bf16x8, A2), __builtin_bit_cast(bf16x8, B2d), G, 0, 0, 0);
    }

    // Epilogue: out[lam] = sum_l W2[lam,l]*G[l,lam] + b2[lam]*ssum
    float p = 0.f;
    #pragma unroll
    for (int q = 0; q < 4; ++q) {
        const f32x4 wv = *(const f32x4*)(W2 + lam * 32 + 8 * q + 4 * l5);
        p += wv[0] * G[4 * q + 0] + wv[1] * G[4 * q + 1]
           + wv[2] * G[4 * q + 2] + wv[3] * G[4 * q + 3];
    }
    p    += __shfl_xor(p, 32, 64);
    ssum += __shfl_xor(ssum, 32, 64);
    const float o = p + b2[lam] * ssum;
    if (l5 == 0) red[w][lam] = o;
    __syncthreads();
    if (tid < 32)
        out[bn * 32 + tid] = red[0][tid] + red[1][tid] + red[2][tid] + red[3][tid];
}

// ---------- fallback (R10 kernel, f32 LDS staging, no ws needed) ----------
__global__ __launch_bounds__(256, 4)
void filter_L(const float* __restrict__ tensor, const float* __restrict__ rbf,
              const float* __restrict__ rij, const float* __restrict__ W1,
              const float* __restrict__ b1, const float* __restrict__ W2,
              const float* __restrict__ b2, float* __restrict__ out)
{
    const int bn = blockIdx.x, b = bn >> 9, tid = threadIdx.x;
    const int lane = tid & 63, w = tid >> 6, lam = lane & 31, l5 = lane >> 5;
    __shared__ float Ts[4][3072];
    __shared__ unsigned upk[N_][2];
    __shared__ float red[4][32];
    const float* rij_bn = rij + (size_t)bn * (N_ * 3);
    const float* rbf_bn = rbf + (size_t)bn * (N_ * 32);
    const float* ten_b  = tensor + (size_t)b * (N_ * 32 * 3);
    #pragma unroll
    for (int t = 0; t < 2; ++t) {
        const int k = tid + t * 256;
        const float rx = rij_bn[3 * k], ry = rij_bn[3 * k + 1], rz = rij_bn[3 * k + 2];
        const float r2 = rx * rx + ry * ry + rz * rz;
        const float inv = rsqrtf(fmaxf(r2, 1e-8f));
        const float sc = (r2 >= 1e-16f) ? inv : 0.f;
        upk[k][0] = pkbf(rx * sc, ry * sc);
        upk[k][1] = pkbf(rz * sc, 0.f);
    }
    bf16x8 W1b[2];
    {
        const float* p1 = W1 + lam * 32 + 8 * l5;
        const f32x4 a0 = ((const f32x4*)p1)[0], a1 = ((const f32x4*)p1)[1];
        const f32x4 a2 = ((const f32x4*)(p1 + 16))[0], a3 = ((const f32x4*)(p1 + 16))[1];
        #pragma unroll
        for (int e = 0; e < 4; ++e) {
            W1b[0][e] = __builtin_bit_cast(short, __float2bfloat16(a0[e]));
            W1b[0][4 + e] = __builtin_bit_cast(short, __float2bfloat16(a1[e]));
            W1b[1][e] = __builtin_bit_cast(short, __float2bfloat16(a2[e]));
            W1b[1][4 + e] = __builtin_bit_cast(short, __float2bfloat16(a3[e]));
        }
    }
    const float b1s = b1[lam];
    __syncthreads();
    float* tsw = &Ts[w][0];
    f32x4 xa[2], xb[2], xc[2], xd[2];
    {
        const float* ap = rbf_bn + (size_t)(w * 128 + lam) * 32 + 8 * l5;
        xa[0] = ((const f32x4*)ap)[0]; xb[0] = ((const f32x4*)ap)[1];
        xc[0] = ((const f32x4*)(ap + 16))[0]; xd[0] = ((const f32x4*)(ap + 16))[1];
    }
    {
        const float* gsrc = ten_b + (size_t)(w * 128) * 96;
        #pragma unroll
        for (int it = 0; it < 12; ++it) gl2lds16(gsrc + it * 256 + lane * 4, tsw + it * 256);
    }
    f32x16 G;
    #pragma unroll
    for (int i = 0; i < 16; ++i) G[i] = 0.f;
    float ssum = 0.f;
    #pragma unroll
    for (int j = 0; j < 4; ++j) {
        const int e0 = (w * 4 + j) * 32, cur = j & 1, nx = cur ^ 1;
        bf16x8 X0, X1;
        #pragma unroll
        for (int e = 0; e < 4; ++e) {
            X0[e] = __builtin_bit_cast(short, __float2bfloat16(xa[cur][e]));
            X0[4 + e] = __builtin_bit_cast(short, __float2bfloat16(xb[cur][e]));
            X1[e] = __builtin_bit_cast(short, __float2bfloat16(xc[cur][e]));
            X1[4 + e] = __builtin_bit_cast(short, __float2bfloat16(xd[cur][e]));
        }
        if (j < 3) {
            const float* ap = rbf_bn + (size_t)(e0 + 32 + lam) * 32 + 8 * l5;
            xa[nx] = ((const f32x4*)ap)[0]; xb[nx] = ((const f32x4*)ap)[1];
            xc[nx] = ((const f32x4*)(ap + 16))[0]; xd[nx] = ((const f32x4*)(ap + 16))[1];
        }
        f32x16 h;
        #pragma unroll
        for (int i = 0; i < 16; ++i) h[i] = 0.f;
        h = __builtin_amdgcn_mfma_f32_32x32x16_bf16(X0, W1b[0], h, 0, 0, 0);
        h = __builtin_amdgcn_mfma_f32_32x32x16_bf16(X1, W1b[1], h, 0, 0, 0);
        unsigned P0, P1, P2, P3, P4, P5, P6, P7;
        {
            const float t0 = fmaxf(h[0] + b1s, 0.f), t1v = fmaxf(h[1] + b1s, 0.f);
            const float t2v = fmaxf(h[2] + b1s, 0.f), t3 = fmaxf(h[3] + b1s, 0.f);
            const float t4 = fmaxf(h[4] + b1s, 0.f), t5 = fmaxf(h[5] + b1s, 0.f);
            const float t6 = fmaxf(h[6] + b1s, 0.f), t7 = fmaxf(h[7] + b1s, 0.f);
            const float t8 = fmaxf(h[8] + b1s, 0.f), t9 = fmaxf(h[9] + b1s, 0.f);
            const float tA = fmaxf(h[10] + b1s, 0.f), tB = fmaxf(h[11] + b1s, 0.f);
            const float tC = fmaxf(h[12] + b1s, 0.f), tD = fmaxf(h[13] + b1s, 0.f);
            const float tE = fmaxf(h[14] + b1s, 0.f), tF = fmaxf(h[15] + b1s, 0.f);
            P0 = pkbf(t0, t1v); P1 = pkbf(t2v, t3); P2 = pkbf(t4, t5); P3 = pkbf(t6, t7);
            P4 = pkbf(t8, t9); P5 = pkbf(tA, tB); P6 = pkbf(tC, tD); P7 = pkbf(tE, tF);
        }
        const unsigned Q0 = __shfl_xor(P0, 32, 64), Q1 = __shfl_xor(P1, 32, 64);
        const unsigned Q2 = __shfl_xor(P2, 32, 64), Q3 = __shfl_xor(P3, 32, 64);
        const unsigned Q4 = __shfl_xor(P4, 32, 64), Q5 = __shfl_xor(P5, 32, 64);
        const unsigned Q6 = __shfl_xor(P6, 32, 64), Q7 = __shfl_xor(P7, 32, 64);
        const bool lo = (l5 == 0);
        const u32x4 A1 = { lo ? P0 : Q2, lo ? P1 : Q3, lo ? Q0 : P2, lo ? Q1 : P3 };
        const u32x4 A2 = { lo ? P4 : Q6, lo ? P5 : Q7, lo ? Q4 : P6, lo ? Q5 : P7 };
        if (j < 3) asm volatile("s_waitcnt vmcnt(4)" ::: "memory");
        else       asm volatile("s_waitcnt vmcnt(0)" ::: "memory");
        u32x4 B1d, B2d;
        float sp;
        #pragma unroll
        for (int e = 0; e < 8; ++e) {
            const int kl = 8 * l5 + e;
            const unsigned u0 = upk[e0 + kl][0], u1 = upk[e0 + kl][1];
            const float* tq = tsw + kl * 96 + 3 * lam;
            const float s = bflo2f(u0) * tq[0] + bfhi2f(u0) * tq[1] + bflo2f(u1) * tq[2];
            ssum += s;
            if (e & 1) B1d[e >> 1] = pkbf(sp, s); else sp = s;
        }
        #pragma unroll
        for (int e = 0; e < 8; ++e) {
            const int kl = 16 + 8 * l5 + e;
            const unsigned u0 = upk[e0 + kl][0], u1 = upk[e0 + kl][1];
            const float* tq = tsw + kl * 96 + 3 * lam;
            const float s = bflo2f(u0) * tq[0] + bfhi2f(u0) * tq[1] + bflo2f(u1) * tq[2];
            ssum += s;
            if (e & 1) B2d[e >> 1] = pkbf(sp, s); else sp = s;
        }
        asm volatile("s_waitcnt lgkmcnt(0)" ::: "memory");
        if (j < 3) {
            const float* gsrc = ten_b + (size_t)(e0 + 32) * 96;
            #pragma unroll
            for (int it = 0; it < 12; ++it) gl2lds16(gsrc + it * 256 + lane * 4, tsw + it * 256);
        }
        G = __builtin_amdgcn_mfma_f32_32x32x16_bf16(
                __builtin_bit_cast(bf16x8, A1), __builtin_bit_cast(bf16x8, B1d), G, 0, 0, 0);
        G = __builtin_amdgcn_mfma_f32_32x32x16_bf16(
                __builtin_bit_cast(bf16x8, A2), __builtin_bit_cast(bf16x8, B2d), G, 0, 0, 0);
    }
    float p = 0.f;
    #pragma unroll
    for (int q = 0; q < 4; ++q) {
        const f32x4 wv = *(const f32x4*)(W2 + lam * 32 + 8 * q + 4 * l5);
        p += wv[0] * G[4 * q + 0] + wv[1] * G[4 * q + 1]
           + wv[2] * G[4 * q + 2] + wv[3] * G[4 * q + 3];
    }
    p    += __shfl_xor(p, 32, 64);
    ssum += __shfl_xor(ssum, 32, 64);
    const float o = p + b2[lam] * ssum;
    if (l5 == 0) red[w][lam] = o;
    __syncthreads();
    if (tid < 32)
        out[bn * 32 + tid] = red[0][tid] + red[1][tid] + red[2][tid] + red[3][tid];
}

extern "C" void kernel_launch(void* const* d_in, const int* in_sizes, int n_in,
                              void* d_out, int out_size, void* d_ws, size_t ws_size,
                              hipStream_t stream) {
    const float* tensor = (const float*)d_in[0];
    const float* rbf    = (const float*)d_in[1];
    const float* rij    = (const float*)d_in[2];
    const float* W1     = (const float*)d_in[3];
    const float* b1     = (const float*)d_in[4];
    const float* W2     = (const float*)d_in[5];
    const float* b2     = (const float*)d_in[6];
    float* out = (float*)d_out;

    const size_t ws_need = (size_t)2 * N_ * 32 * 2 * sizeof(unsigned);   // 512 KB
    dim3 block(256), grid(2 * N_);
    if (ws_size >= ws_need) {
        unsigned* tw = (unsigned*)d_ws;
        pack_tensor<<<dim3(256), block, 0, stream>>>(tensor, tw);
        filter_S<<<grid, block, 0, stream>>>(tw, rbf, rij, W1, b1, W2, b2, out);
    } else {
        filter_L<<<grid, block, 0, stream>>>(tensor, rbf, rij, W1, b1, W2, b2, out);
    }
}